// Round 2
// baseline (1132.068 us; speedup 1.0000x reference)
//
#include <hip/hip_runtime.h>
#include <cstddef>

namespace {

constexpr int   kN    = 512;
constexpr int   kB    = 64;
constexpr float kAlpha = 0.8f;
constexpr float kBig  = 1e8f;
constexpr float kKexp = 144.26950408889634f;    // (1/gamma) * log2(e)
constexpr float kGLn2 = 0.006931471805599453f;  // gamma * ln(2)
constexpr float kWexp = 0.07213475204444817f;   // G * log2(e)

// diag-packed index within a 64x64 tile (4096 floats); diag s in [0,126]
__device__ __forceinline__ int bidx(int s, int u) {
    int sc = s < 0 ? 0 : s;
    int umin = (sc > 63) ? (sc - 63) : 0;
    int p = (sc < 64) ? ((sc * (sc + 1)) >> 1)
                      : (4096 - (((127 - sc) * (128 - sc)) >> 1));
    int ix = p + u - umin;
    ix = ix < 0 ? 0 : ix;
    return ix > 4095 ? 4095 : ix;
}

__global__ __launch_bounds__(512)
void dilate_tiled(const float* __restrict__ input,
                  const float* __restrict__ target,
                  float* __restrict__ Rg,        // per-block 64*4096 floats
                  float* __restrict__ partials,  // [kB]
                  int b0) {
    __shared__ float sx[512], st_[512], sw_[512];
    __shared__ float bH_R[512], bH_E[512], bV_R[512], bV_E[512];
    __shared__ float ccF[64], ccBE[64], ccBR[64];
    __shared__ float sred[8];
    __shared__ float s_rnn;

    const int tid = threadIdx.x;
    const int w = tid >> 6;       // wave = tile-row
    const int u = tid & 63;       // lane = row within tile
    const int b = b0 + blockIdx.x;
    float* __restrict__ Rslot = Rg + (size_t)blockIdx.x * (size_t)(64 * 4096);

    sx[tid]  = input[(size_t)b * kN + tid];
    st_[tid] = target[(size_t)b * kN + tid];
    bH_R[tid] = kBig;   // top boundary for tile-row 0 reads BIG
    bV_R[tid] = kBig;   // left boundary for tile-col 0 reads BIG

    // normalized exponential time weights
    float ew = exp2f(kWexp * (float)tid);
    float wsum = ew;
    #pragma unroll
    for (int off = 32; off; off >>= 1) wsum += __shfl_xor(wsum, off);
    if (u == 0) sred[w] = wsum;
    __syncthreads();
    float tot = 0.f;
    #pragma unroll
    for (int q = 0; q < 8; ++q) tot += sred[q];
    sw_[tid] = ew * (512.0f / tot);
    __syncthreads();

    const int r = w;
    const int gi = (r << 6) + u;              // 0-based global row (i-1)
    const float tcur = st_[gi];
    const float wcur = sw_[gi];
    const int gi1 = gi + 1 > 511 ? 511 : gi + 1;
    const float tn = st_[gi1];                // t for row i+1
    const float wn = sw_[gi1];

    // ---------------- forward soft-DTW ----------------
    for (int d = 0; d < 15; ++d) {
        if (d >= r && d <= r + 7) {
            const int c = d - r;
            float* __restrict__ tb = Rslot + (((r << 3) + c) << 12);
            float vC = bV_R[(r << 6) | u];    // R(i, 64c) from left tile
            float vA = __shfl_up(vC, 1);      // R(i-1, 64c)
            float corner;
            if (r == 0)      corner = (c == 0) ? 0.0f : kBig;
            else if (c == 0) corner = kBig;
            else             corner = ccF[((r - 1) << 3) + (c - 1)];
            if (u == 0) vA = corner;
            float prev = kBig, prev2 = kBig, hbA = kBig;
            int pos = 0;
            const int xbase = (c << 6) - u;   // x index = xbase + s
            for (int s = 0; s < 127; ++s) {
                const int v = s - u;
                const int umin = (s > 63) ? (s - 63) : 0;
                float A = __shfl_up(prev2, 1);     // R(i-1, j-1)
                float B = __shfl_up(prev, 1);      // R(i-1, j)
                const int smin = s > 63 ? 63 : s;
                const float hbB = bH_R[(c << 6) | smin];
                if (u == 0) { A = hbA; B = hbB; }
                float C = prev;                    // R(i, j-1)
                if (v == 0) { A = vA; C = vC; }
                int xi = xbase + s;
                xi = xi < 0 ? 0 : (xi > 511 ? 511 : xi);
                const float dx = tcur - sx[xi];
                const float dc = wcur * dx * dx;
                const float m = fminf(A, fminf(B, C));
                const float ssum = exp2f((m - A) * kKexp)
                                 + exp2f((m - B) * kKexp)
                                 + exp2f((m - C) * kKexp);
                float cur = dc + m - kGLn2 * log2f(ssum);
                const bool valid = (v >= 0) && (v <= 63);
                cur = valid ? cur : kBig;
                if (valid) tb[pos + (u - umin)] = cur;
                if (s >= 63) {
                    if (u == 63) bH_R[(c << 6) | v] = cur;   // bottom row out
                    if (v == 63) bV_R[(r << 6) | u] = cur;   // right col out
                    if (s == 126 && u == 63) {
                        ccF[(r << 3) + c] = cur;             // corner out
                        if (r == 7 && c == 7) s_rnn = cur;   // R[N,N]
                    }
                }
                hbA = hbB;
                prev2 = prev; prev = cur;
                pos += (s < 64) ? (s + 1) : (127 - s);
            }
        }
        __syncthreads();
    }

    // ---------------- backward adjoint (E = dR/dD) ----------------
    float acc = 0.0f;
    for (int D = 14; D >= 0; --D) {
        if (D >= r && D <= r + 7) {
            const int c = D - r;
            const float* __restrict__ tb = Rslot + (((r << 3) + c) << 12);
            float vRE = bV_E[(r << 6) | u];   // right-tile left col E
            float vRR = bV_R[(r << 6) | u];   // right-tile left col R
            const float shvE = __shfl_down(vRE, 1);
            const float shvR = __shfl_down(vRR, 1);
            float cornE = 0.0f, cornR = 0.0f;
            if (r < 7 && c < 7) {
                cornE = ccBE[((r + 1) << 3) + (c + 1)];
                cornR = ccBR[((r + 1) << 3) + (c + 1)];
            }
            float Eprev = 0.f, Eprev2 = 0.f, Rprev = 0.f, Rprev2 = 0.f;
            float hbEv1 = 0.f, hbRv1 = 0.f;
            int xn0 = (c << 6) + 127 - u;
            xn0 = xn0 > 511 ? 511 : xn0;
            float xnext = sx[xn0];
            // depth-3 prefetch pipeline for this tile's R
            float p0 = tb[bidx(126, u)];
            float p1 = tb[bidx(125, u)];
            float p2 = tb[bidx(124, u)];
            const float dij0 = (float)(((r - c) << 6) + 2 * u);
            const int xbase = (c << 6) - u;
            const bool mDrow = (r < 7);
            const bool mRcol = (c < 7);
            for (int s = 126; s >= 0; --s) {
                const int v = s - u;
                const bool valid = (v >= 0) && (v <= 63);
                const float Rv = p0;
                float Ed = __shfl_down(Eprev, 1);    // (u+1, v)
                float Rd = __shfl_down(Rprev, 1);
                float Eg = __shfl_down(Eprev2, 1);   // (u+1, v+1)
                float Rg2 = __shfl_down(Rprev2, 1);
                int vbc = s - 63; vbc = vbc < 0 ? 0 : vbc;
                const float hbEv = bH_E[(c << 6) | vbc];
                const float hbRv = bH_R[(c << 6) | vbc];
                if (v == 63) { Eg = shvE; Rg2 = shvR; }
                if (u == 63) { Ed = hbEv; Rd = hbRv; Eg = hbEv1; Rg2 = hbRv1; }
                float Er = Eprev, Rr = Rprev;        // (u, v+1)
                if (v == 63) { Er = vRE; Rr = vRR; }
                if (u == 63 && v == 63) { Eg = cornE; Rg2 = cornR; }
                const bool mD = mDrow || (u < 63);
                const bool mR = mRcol || (v < 63);
                int xi = xbase + s;
                xi = xi < 0 ? 0 : (xi > 511 ? 511 : xi);
                const float xcur = sx[xi];
                const float e1 = tn - xcur;          // d(i+1, j)
                const float e2 = tcur - xnext;       // d(i, j+1)
                const float e3 = tn - xnext;         // d(i+1, j+1)
                const float ddn = wn * e1 * e1;
                const float drt = wcur * e2 * e2;
                const float ddg = wn * e3 * e3;
                float t1 = Ed * exp2f((Rd - ddn - Rv) * kKexp);
                float t2 = Er * exp2f((Rr - drt - Rv) * kKexp);
                float t3 = Eg * exp2f((Rg2 - ddg - Rv) * kKexp);
                t1 = mD ? t1 : 0.0f;
                t2 = mR ? t2 : 0.0f;
                t3 = (mD && mR) ? t3 : 0.0f;
                float Ev = t1 + t2 + t3;
                if (r == 7 && c == 7 && s == 126) Ev = 1.0f;  // seed E[N,N]
                Ev = valid ? Ev : 0.0f;
                const float dij = dij0 - (float)s;
                acc = fmaf(Ev, dij * dij, acc);
                if (s <= 63) {
                    if (u == 0) { bH_E[(c << 6) | s] = Ev;
                                  bH_R[(c << 6) | s] = Rv; }
                    if (v == 0) { bV_E[(r << 6) | u] = Ev;
                                  bV_R[(r << 6) | u] = Rv; }
                    if (s == 0 && u == 0) {
                        ccBE[(r << 3) + c] = Ev;
                        ccBR[(r << 3) + c] = Rv;
                    }
                }
                Eprev2 = Eprev; Eprev = Ev;
                Rprev2 = Rprev; Rprev = Rv;
                hbEv1 = hbEv; hbRv1 = hbRv;
                xnext = xcur;
                p0 = p1; p1 = p2;
                p2 = tb[bidx(s - 3, u)];
            }
        }
        __syncthreads();
    }

    // ---- reduce temporal term, emit per-batch partial ----
    float a = acc;
    #pragma unroll
    for (int off = 32; off; off >>= 1) a += __shfl_xor(a, off);
    if (u == 0) sred[w] = a;
    __syncthreads();
    if (tid == 0) {
        float ts = 0.f;
        #pragma unroll
        for (int q = 0; q < 8; ++q) ts += sred[q];
        const float temporal = ts * (1.0f / ((float)kN * (float)kN));
        partials[b] = (kAlpha * s_rnn + (1.0f - kAlpha) * temporal)
                    * (1.0f / (float)kB);
    }
}

__global__ void dilate_finalize(const float* __restrict__ partials,
                                float* __restrict__ out) {
    float v = partials[threadIdx.x];   // 64 threads = one wave
    #pragma unroll
    for (int off = 32; off > 0; off >>= 1) v += __shfl_down(v, off);
    if (threadIdx.x == 0) out[0] = v;
}

} // namespace

extern "C" void kernel_launch(void* const* d_in, const int* in_sizes, int n_in,
                              void* d_out, int out_size, void* d_ws, size_t ws_size,
                              hipStream_t stream) {
    (void)in_sizes; (void)n_in; (void)out_size;
    const float* input  = (const float*)d_in[0];
    const float* target = (const float*)d_in[1];
    float* out      = (float*)d_out;
    float* partials = (float*)d_ws;                       // kB floats
    float* Rbase    = (float*)((char*)d_ws + 1024);       // R slots

    const size_t per_batch = (size_t)64 * 4096 * sizeof(float);  // 1 MiB
    const size_t avail = (ws_size > 1024) ? (ws_size - 1024) : 0;
    int cap = (int)(avail / per_batch);
    if (cap > kB) cap = kB;
    if (cap < 1)  cap = 1;

    for (int b0 = 0; b0 < kB; b0 += cap) {
        const int nb = (kB - b0 < cap) ? (kB - b0) : cap;
        hipLaunchKernelGGL(dilate_tiled, dim3(nb), dim3(512), 0, stream,
                           input, target, Rbase, partials, b0);
    }
    hipLaunchKernelGGL(dilate_finalize, dim3(1), dim3(64), 0, stream,
                       partials, out);
}